// Round 3
// baseline (2448.633 us; speedup 1.0000x reference)
//
#include <hip/hip_runtime.h>
#include <math.h>

#define NN 8192
#define NH 1024

typedef __bf16 bf16x8 __attribute__((ext_vector_type(8)));
typedef float floatx4 __attribute__((ext_vector_type(4)));
typedef unsigned short us8 __attribute__((ext_vector_type(8)));
typedef unsigned short us;

__device__ __forceinline__ unsigned short f2bf(float f) {
  unsigned int u = __float_as_uint(f);
  u += 0x7fffu + ((u >> 16) & 1u);
  return (unsigned short)(u >> 16);
}

__device__ __forceinline__ void async16(const void* g, void* l) {
  __builtin_amdgcn_global_load_lds(
      (__attribute__((address_space(1))) void*)(g),
      (__attribute__((address_space(3))) void*)(l), 16, 0, 0);
}

// ===== big GEMM (K=8192, EPI0): sup = 0.3*(A@Bt^T) + 0.7*h0 =================
// 256x128 block tile, 512 threads (8 waves, 64x64 wave tile, 2 waves/SIMD),
// grid 256 (1 block/CU), 96 KB LDS, 4 static stages, counted vmcnt(6).
// Phase-split schedule (T3+T5): per K-step
//   [vmcnt(6)+bar] -> 8 ds_read || 3 stage-issues -> [bar+lgkm(0)+SB0]
//   -> setprio(1) 16-MFMA pure cluster setprio(0)
// Bank-conflict XOR swizzle (source-permuted chunk + read-side XOR) from R1.
__global__ __launch_bounds__(512)
void gemm_big(const us* __restrict__ A, const us* __restrict__ Bt,
              const float* __restrict__ aux, float* __restrict__ supf,
              us* __restrict__ supb)
{
  __shared__ __align__(16) us lsm[49152];  // 96 KB
  us* lB = lsm;            // stage s at s*4096
  us* lA = lsm + 16384;    // stage s at s*8192

  const int id = blockIdx.x;
  const int yt = id & 31;   // M-tile: ids of one stripe differ by 32 -> same XCD
  const int xt = id >> 5;

  const int tid  = threadIdx.x;
  const int lane = tid & 63;
  const int wave = tid >> 6;
  const long tileM = (long)yt * 256;
  const long tileN = (long)xt * 128;
  const int wm = (wave & 3) * 64;
  const int wn = (wave >> 2) * 64;

  // physical chunk p=(tid&3) of row r holds logical chunk p ^ ((r>>1)&3)
  const int chunk = (tid & 3) ^ ((tid >> 3) & 3);
  const us* gAp = A + (tileM + (tid >> 2)) * 8192L + chunk * 8;
  const us* gBp = Bt + (tileN + (tid >> 2)) * 8192L + chunk * 8;
  const int lo = tid * 8;

  const int fr = lane & 15;
  const int q8 = (lane >> 4) * 8;
  const int q8x = q8 ^ ((fr & 6) << 2);  // read-side swizzle

  floatx4 zero4 = {0.f, 0.f, 0.f, 0.f};
  floatx4 acc[4][4];
#pragma unroll
  for (int i = 0; i < 4; ++i)
#pragma unroll
    for (int j = 0; j < 4; ++j) acc[i][j] = zero4;

#define STAGE_BIG(s, kf)                                                  \
  {                                                                       \
    const long ko = (long)(kf) << 5;                                      \
    async16(gAp + ko, lA + (s)*8192 + lo);                                \
    async16(gAp + 128 * 8192L + ko, lA + (s)*8192 + 4096 + lo);           \
    async16(gBp + ko, lB + (s)*4096 + lo);                                \
  }

// Per K-step: ready-wait, memory phase (ds_read + stage-issue), align barrier,
// pure 16-MFMA cluster under setprio. lgkm(0)+sched_barrier(0) per rule #18.
#define KSTEP_BIG(s, kf)                                                  \
  {                                                                       \
    asm volatile("s_waitcnt vmcnt(6)" ::: "memory");                      \
    __builtin_amdgcn_s_barrier();                                         \
    bf16x8 af[4], bfr[4];                                                 \
    _Pragma("unroll") for (int i = 0; i < 4; ++i)                         \
        af[i] = *(const bf16x8*)&lA[(s)*8192 + (wm + 16 * i + fr) * 32 + q8x]; \
    _Pragma("unroll") for (int j = 0; j < 4; ++j)                         \
        bfr[j] = *(const bf16x8*)&lB[(s)*4096 + (wn + 16 * j + fr) * 32 + q8x]; \
    STAGE_BIG((((s) + 3) & 3), kf);                                       \
    __builtin_amdgcn_s_barrier();                                         \
    asm volatile("s_waitcnt lgkmcnt(0)" ::: "memory");                    \
    __builtin_amdgcn_sched_barrier(0);                                    \
    __builtin_amdgcn_s_setprio(1);                                        \
    _Pragma("unroll") for (int i = 0; i < 4; ++i)                         \
        _Pragma("unroll") for (int j = 0; j < 4; ++j)                     \
            acc[i][j] = __builtin_amdgcn_mfma_f32_16x16x32_bf16(          \
                af[i], bfr[j], acc[i][j], 0, 0, 0);                       \
    __builtin_amdgcn_s_setprio(0);                                        \
    __builtin_amdgcn_sched_barrier(0);                                    \
  }

  // prologue: tiles 0,1,2 -> stages 0,1,2 (9 loads in flight per wave)
  STAGE_BIG(0, 0)
  STAGE_BIG(1, 1)
  STAGE_BIG(2, 2)

  for (int kt = 0; kt < 256; kt += 4) {
    int k3 = kt + 3; if (k3 > 255) k3 = 255;
    int k4 = kt + 4; if (k4 > 255) k4 = 255;
    int k5 = kt + 5; if (k5 > 255) k5 = 255;
    int k6 = kt + 6; if (k6 > 255) k6 = 255;
    KSTEP_BIG(0, k3)
    KSTEP_BIG(1, k4)
    KSTEP_BIG(2, k5)
    KSTEP_BIG(3, k6)
  }
  asm volatile("s_waitcnt vmcnt(0)" ::: "memory");

  const int crow = (lane >> 4) * 4;
#pragma unroll
  for (int i = 0; i < 4; ++i)
#pragma unroll
    for (int j = 0; j < 4; ++j)
#pragma unroll
      for (int r = 0; r < 4; ++r) {
        long row = tileM + wm + 16 * i + crow + r;
        long col = tileN + wn + 16 * j + fr;
        long idx = row * NH + col;
        float s = 0.3f * acc[i][j][r] + 0.7f * aux[idx];
        supf[idx] = s;
        supb[idx] = f2bf(s);
      }
#undef STAGE_BIG
#undef KSTEP_BIG
}

// ===== small GEMM (K=1024 fixed) + epilogue =================================
// Upgraded from __syncthreads 2-stage (drains vmcnt(0) every step) to 4-stage
// counted vmcnt(8) + phase-split schedule, mirroring gemm_big. 64 KB LDS,
// grid 512 = 2 blocks/CU (128 KB/CU <= 160). 4 waves, 64x64 wave tile.
// EPI 1: o = relu(th*acc + (1-th)*aux + iof); write iof(hf), fused-T -> hTb
// EPI 2: o = elu(...);                        write iof(hf), outb(hb)
template<int EPI>
__global__ __launch_bounds__(256)
void gemm_db(const us* __restrict__ A, const us* __restrict__ Bt, int K,
             const float* __restrict__ aux, float* __restrict__ iof,
             us* __restrict__ outb, us* __restrict__ hTb, float theta)
{
  __shared__ __align__(16) us lsm[32768];  // 64 KB: 4 stages x (8KB A + 8KB B)
  us* lB = lsm;            // stage s at s*4096
  us* lA = lsm + 16384;    // stage s at s*4096

  const int id = blockIdx.x;
  const int xcd = id & 7, slot = id >> 3;
  const int xt = slot & 7;
  const int yt = xcd + 8 * (slot >> 3);

  const int tid  = threadIdx.x;
  const int lane = tid & 63;
  const int wave = tid >> 6;
  const long tileM = (long)yt * 128;
  const long tileN = (long)xt * 128;
  const int wm = (wave & 1) * 64;
  const int wn = (wave >> 1) * 64;

  const int chunk = (tid & 3) ^ ((tid >> 3) & 3);
  const us* gA0 = A + (tileM + (tid >> 2)) * (long)K + chunk * 8;
  const us* gA1 = gA0 + 64L * K;
  const us* gB0 = Bt + (tileN + (tid >> 2)) * (long)K + chunk * 8;
  const us* gB1 = gB0 + 64L * K;
  const int lo = tid * 8;

  const int fr = lane & 15;
  const int q8 = (lane >> 4) * 8;
  const int q8x = q8 ^ ((fr & 6) << 2);

  floatx4 zero4 = {0.f, 0.f, 0.f, 0.f};
  floatx4 acc[4][4];
#pragma unroll
  for (int i = 0; i < 4; ++i)
#pragma unroll
    for (int j = 0; j < 4; ++j) acc[i][j] = zero4;

#define STAGE_DB(s, kf)                                                   \
  {                                                                       \
    const int k0 = (kf) << 5;                                             \
    async16(gA0 + k0, lA + (s)*4096 + lo);                                \
    async16(gA1 + k0, lA + (s)*4096 + 2048 + lo);                         \
    async16(gB0 + k0, lB + (s)*4096 + lo);                                \
    async16(gB1 + k0, lB + (s)*4096 + 2048 + lo);                         \
  }

#define KSTEP_DB(s, kf)                                                   \
  {                                                                       \
    asm volatile("s_waitcnt vmcnt(8)" ::: "memory");                      \
    __builtin_amdgcn_s_barrier();                                         \
    bf16x8 af[4], bfr[4];                                                 \
    _Pragma("unroll") for (int i = 0; i < 4; ++i)                         \
        af[i] = *(const bf16x8*)&lA[(s)*4096 + (wm + 16 * i + fr) * 32 + q8x]; \
    _Pragma("unroll") for (int j = 0; j < 4; ++j)                         \
        bfr[j] = *(const bf16x8*)&lB[(s)*4096 + (wn + 16 * j + fr) * 32 + q8x]; \
    STAGE_DB((((s) + 3) & 3), kf);                                        \
    __builtin_amdgcn_s_barrier();                                         \
    asm volatile("s_waitcnt lgkmcnt(0)" ::: "memory");                    \
    __builtin_amdgcn_sched_barrier(0);                                    \
    __builtin_amdgcn_s_setprio(1);                                        \
    _Pragma("unroll") for (int i = 0; i < 4; ++i)                         \
        _Pragma("unroll") for (int j = 0; j < 4; ++j)                     \
            acc[i][j] = __builtin_amdgcn_mfma_f32_16x16x32_bf16(          \
                af[i], bfr[j], acc[i][j], 0, 0, 0);                       \
    __builtin_amdgcn_s_setprio(0);                                        \
    __builtin_amdgcn_sched_barrier(0);                                    \
  }

  // K = 1024 always here: 32 K-steps. Prologue: stages 0,1,2 (12 in flight).
  STAGE_DB(0, 0)
  STAGE_DB(1, 1)
  STAGE_DB(2, 2)

  for (int kt = 0; kt < 32; kt += 4) {
    int k3 = kt + 3; if (k3 > 31) k3 = 31;
    int k4 = kt + 4; if (k4 > 31) k4 = 31;
    int k5 = kt + 5; if (k5 > 31) k5 = 31;
    int k6 = kt + 6; if (k6 > 31) k6 = 31;
    KSTEP_DB(0, k3)
    KSTEP_DB(1, k4)
    KSTEP_DB(2, k5)
    KSTEP_DB(3, k6)
  }
  asm volatile("s_waitcnt vmcnt(0)" ::: "memory");
  __syncthreads();

  us* ldsT = lsm;  // [col][row], stride 136 (EPI 1 only)
  const int crow = (lane >> 4) * 4;
#pragma unroll
  for (int i = 0; i < 4; ++i) {
#pragma unroll
    for (int j = 0; j < 4; ++j) {
#pragma unroll
      for (int r = 0; r < 4; ++r) {
        int lr = wm + 16 * i + crow + r;
        int lc = wn + 16 * j + fr;
        long idx = (tileM + lr) * NH + tileN + lc;
        float o = theta * acc[i][j][r] + (1.f - theta) * aux[idx] + iof[idx];
        o = (EPI == 1) ? fmaxf(o, 0.f) : (o > 0.f ? o : __expf(o) - 1.f);
        iof[idx] = o;
        if (EPI == 1) ldsT[lc * 136 + lr] = f2bf(o);
        if (EPI == 2) outb[idx] = f2bf(o);
      }
    }
  }
  if (EPI == 1) {
    __syncthreads();
    int c = tid >> 1, half = tid & 1;
#pragma unroll
    for (int it = 0; it < 8; ++it) {
      int r = half * 64 + it * 8;
      us8 v = *(const us8*)&ldsT[c * 136 + r];
      *(us8*)&hTb[(tileN + c) * 8192L + tileM + r] = v;
    }
  }
#undef STAGE_DB
#undef KSTEP_DB
}

// ======== classifier head as MFMA GEMM: out = sigmoid(relu(h@W1+b1)@W3+b3) ===
__global__ __launch_bounds__(256)
void cls_gemm(const us* __restrict__ hb, const us* __restrict__ W1t,
              const float* __restrict__ b1, const float* __restrict__ W3,
              const float* __restrict__ b3, float* __restrict__ out)
{
  __shared__ __align__(16) us lA[4096];
  __shared__ __align__(16) us lB[2048];
  const int tid = threadIdx.x, lane = tid & 63, wave = tid >> 6;
  const long tileM = (long)blockIdx.x * 128;
  const us* gA0 = hb + (tileM + (tid >> 2)) * 1024L + (tid & 3) * 8;
  const us* gA1 = gA0 + 64 * 1024L;
  const us* gB0 = W1t + (tid >> 2) * 1024L + (tid & 3) * 8;
  const int fr = lane & 15, q8 = (lane >> 4) * 8;
  const int wm = wave * 32;

  floatx4 zero4 = {0.f, 0.f, 0.f, 0.f};
  floatx4 acc[2][4];
#pragma unroll
  for (int i = 0; i < 2; ++i)
#pragma unroll
    for (int j = 0; j < 4; ++j) acc[i][j] = zero4;

  for (int kt = 0; kt < 32; ++kt) {
    const int k0 = kt << 5;
    async16(gA0 + k0, lA + tid * 8);
    async16(gA1 + k0, lA + 2048 + tid * 8);
    async16(gB0 + k0, lB + tid * 8);
    __syncthreads();
    bf16x8 af[2], bfr[4];
#pragma unroll
    for (int i = 0; i < 2; ++i)
      af[i] = *(const bf16x8*)&lA[(wm + 16 * i + fr) * 32 + q8];
#pragma unroll
    for (int j = 0; j < 4; ++j)
      bfr[j] = *(const bf16x8*)&lB[(16 * j + fr) * 32 + q8];
#pragma unroll
    for (int i = 0; i < 2; ++i)
#pragma unroll
      for (int j = 0; j < 4; ++j)
        acc[i][j] = __builtin_amdgcn_mfma_f32_16x16x32_bf16(af[i], bfr[j], acc[i][j], 0, 0, 0);
    __syncthreads();
  }

  float b1v[4], w3v[4];
#pragma unroll
  for (int j = 0; j < 4; ++j) { b1v[j] = b1[16 * j + fr]; w3v[j] = W3[16 * j + fr]; }
  const float b3v = b3[0];
  const int crow = (lane >> 4) * 4;
#pragma unroll
  for (int i = 0; i < 2; ++i)
#pragma unroll
    for (int r = 0; r < 4; ++r) {
      float v = 0.f;
#pragma unroll
      for (int j = 0; j < 4; ++j)
        v += fmaxf(acc[i][j][r] + b1v[j], 0.f) * w3v[j];
      v += __shfl_xor(v, 1);
      v += __shfl_xor(v, 2);
      v += __shfl_xor(v, 4);
      v += __shfl_xor(v, 8);
      if (fr == 0)
        out[tileM + wm + 16 * i + crow + r] = 1.f / (1.f + __expf(-(v + b3v)));
    }
}

// ---------------- fp32 (R x C) -> bf16 transposed (C x R) ----------------
__global__ __launch_bounds__(256)
void transpose_f32_bf16(const float* __restrict__ src, us* __restrict__ dst,
                        int R, int C) {
  __shared__ float t[32][33];
  int tid = threadIdx.x;
  int tx = tid & 31, ty = tid >> 5;
  long r0 = (long)blockIdx.y * 32, c0 = (long)blockIdx.x * 32;
#pragma unroll
  for (int i = 0; i < 32; i += 8)
    t[ty + i][tx] = src[(r0 + ty + i) * C + c0 + tx];
  __syncthreads();
#pragma unroll
  for (int i = 0; i < 32; i += 8)
    dst[(c0 + ty + i) * R + r0 + tx] = f2bf(t[tx][ty + i]);
}

// ---------------- fp32 -> bf16 elementwise (dist) ----------------
__global__ __launch_bounds__(256)
void f32_to_bf16_vec(const float* __restrict__ s, us* __restrict__ d) {
  long i = (blockIdx.x * 256L + threadIdx.x) * 4;
  float4 v = *(const float4*)(s + i);
  *(ushort4*)(d + i) = make_ushort4(f2bf(v.x), f2bf(v.y), f2bf(v.z), f2bf(v.w));
}

// ---------------- h0 = relu(x @ fc_W + fc_b) ----------------
__global__ __launch_bounds__(256)
void fc_kernel(const float* __restrict__ x, const float* __restrict__ W,
               const float* __restrict__ b, float* __restrict__ h0f,
               float* __restrict__ hf) {
  __shared__ float xs[64];
  int row = blockIdx.x, tid = threadIdx.x;
  if (tid < 63) xs[tid] = x[row * 63 + tid];
  __syncthreads();
#pragma unroll
  for (int q = 0; q < 4; ++q) {
    int c = tid + q * 256;
    float s = b[c];
    for (int k = 0; k < 63; ++k) s += xs[k] * W[k * NH + c];
    s = fmaxf(s, 0.f);
    long idx = (long)row * NH + c;
    h0f[idx] = s;
    hf[idx] = s;
  }
}

// ---------------- va1 = gat_W @ a1, va2 = gat_W @ a2 ----------------
__global__ __launch_bounds__(256)
void wv_kernel(const float* __restrict__ W, const float* __restrict__ a,
               float* __restrict__ va1, float* __restrict__ va2) {
  int k = blockIdx.x, tid = threadIdx.x;
  float s1 = 0.f, s2 = 0.f;
  for (int n = tid; n < NH; n += 256) {
    float w = W[(long)k * NH + n];
    s1 += w * a[n];
    s2 += w * a[NH + n];
  }
#pragma unroll
  for (int o = 32; o; o >>= 1) { s1 += __shfl_down(s1, o); s2 += __shfl_down(s2, o); }
  __shared__ float r1[4], r2[4];
  int wave = tid >> 6;
  if ((tid & 63) == 0) { r1[wave] = s1; r2[wave] = s2; }
  __syncthreads();
  if (tid == 0) {
    va1[k] = r1[0] + r1[1] + r1[2] + r1[3];
    va2[k] = r2[0] + r2[1] + r2[2] + r2[3];
  }
}

// ---------------- f = h @ va1, g = h @ va2 ----------------
__global__ __launch_bounds__(256)
void fg_kernel(const float* __restrict__ h, const float* __restrict__ va1,
               const float* __restrict__ va2, float* __restrict__ fv,
               float* __restrict__ gv) {
  int row = blockIdx.x, tid = threadIdx.x;
  float s1 = 0.f, s2 = 0.f;
  for (int k = tid; k < NH; k += 256) {
    float v = h[(long)row * NH + k];
    s1 += v * va1[k];
    s2 += v * va2[k];
  }
#pragma unroll
  for (int o = 32; o; o >>= 1) { s1 += __shfl_down(s1, o); s2 += __shfl_down(s2, o); }
  __shared__ float r1[4], r2[4];
  int wave = tid >> 6;
  if ((tid & 63) == 0) { r1[wave] = s1; r2[wave] = s2; }
  __syncthreads();
  if (tid == 0) {
    fv[row] = r1[0] + r1[1] + r1[2] + r1[3];
    gv[row] = r2[0] + r2[1] + r2[2] + r2[3];
  }
}

// ---------------- attention pass 1: per-row max & denom ----------------
__global__ __launch_bounds__(256)
void attn_ml(const int* __restrict__ adj, const float* __restrict__ f,
             const float* __restrict__ g, float* __restrict__ Mr,
             float* __restrict__ Lr) {
  const int row = blockIdx.x, tid = threadIdx.x;
  const float fi = f[row];
  const int4* arow = (const int4*)(adj + (long)row * NN);
  float m = -3.0e38f, s = 0.f;
  for (int c = tid; c < NN / 4; c += 256) {
    int4 a = arow[c];
    float4 gg = *(const float4*)(g + c * 4);
#pragma unroll
    for (int t = 0; t < 4; ++t) {
      int av = (t == 0) ? a.x : (t == 1) ? a.y : (t == 2) ? a.z : a.w;
      float gvv = (t == 0) ? gg.x : (t == 1) ? gg.y : (t == 2) ? gg.z : gg.w;
      if (av > 0) {
        float e = fi + gvv;
        e = e > 0.f ? e : 0.2f * e;
        if (e > m) { s = s * __expf(m - e) + 1.f; m = e; }
        else s += __expf(e - m);
      }
    }
  }
#pragma unroll
  for (int o = 32; o; o >>= 1) {
    float m2 = __shfl_down(m, o), s2 = __shfl_down(s, o);
    float mn = fmaxf(m, m2);
    s = s * __expf(m - mn) + s2 * __expf(m2 - mn);
    m = mn;
  }
  __shared__ float ms[4], ss[4];
  int wave = tid >> 6;
  if ((tid & 63) == 0) { ms[wave] = m; ss[wave] = s; }
  __syncthreads();
  if (tid == 0) {
    float mm = ms[0], sv = ss[0];
    for (int w = 1; w < 4; ++w) {
      float mn = fmaxf(mm, ms[w]);
      sv = sv * __expf(mm - mn) + ss[w] * __expf(ms[w] - mn);
      mm = mn;
    }
    Mr[row] = mm;
    Lr[row] = sv;
  }
}

// ---------------- attention pass 2: P (bf16) ----------------
__global__ __launch_bounds__(256)
void attn_p(const int* __restrict__ adj, const float* __restrict__ f,
            const float* __restrict__ g, const float* __restrict__ Mr,
            const float* __restrict__ Lr, us* __restrict__ P) {
  long gid = blockIdx.x * 256L + threadIdx.x;
  int row = (int)(gid >> 11);
  int jc = (int)(gid & 2047) * 4;
  float fi = f[row], m = Mr[row], l = Lr[row];
  bool uni = !(l > 0.f);
  float inv = uni ? 0.f : 1.f / l;
  int4 a = *(const int4*)(adj + ((long)row << 13) + jc);
  float4 gg = *(const float4*)(g + jc);
  float p[4];
#pragma unroll
  for (int t = 0; t < 4; ++t) {
    int av = (t == 0) ? a.x : (t == 1) ? a.y : (t == 2) ? a.z : a.w;
    float gvv = (t == 0) ? gg.x : (t == 1) ? gg.y : (t == 2) ? gg.z : gg.w;
    float e = fi + gvv;
    e = e > 0.f ? e : 0.2f * e;
    float pv = (av > 0) ? __expf(e - m) * inv : 0.f;
    if (uni) pv = 1.f / (float)NN;
    p[t] = pv;
  }
  *(ushort4*)(P + ((long)row << 13) + jc) =
      make_ushort4(f2bf(p[0]), f2bf(p[1]), f2bf(p[2]), f2bf(p[3]));
}

extern "C" void kernel_launch(void* const* d_in, const int* in_sizes, int n_in,
                              void* d_out, int out_size, void* d_ws, size_t ws_size,
                              hipStream_t stream) {
  const float* x      = (const float*)d_in[0];
  const float* dist   = (const float*)d_in[1];
  const int*   adj    = (const int*)d_in[2];
  const float* fc_W   = (const float*)d_in[3];
  const float* fc_b   = (const float*)d_in[4];
  const float* conv_W = (const float*)d_in[5];
  const float* gat_W  = (const float*)d_in[6];
  const float* gat_a  = (const float*)d_in[7];
  const float* cls1_W = (const float*)d_in[8];
  const float* cls1_b = (const float*)d_in[9];
  const float* cls3_W = (const float*)d_in[10];
  const float* cls3_b = (const float*)d_in[11];
  float* out = (float*)d_out;

  char* p = (char*)d_ws;
  auto alloc = [&](size_t bytes) {
    char* r = p;
    p += (bytes + 255) & ~(size_t)255;
    return r;
  };
  us* distb   = (us*)alloc((size_t)NN * NN * 2);
  float* h0f  = (float*)alloc((size_t)NN * NH * 4);
  float* hf   = (float*)alloc((size_t)NN * NH * 4);
  float* supf = (float*)alloc((size_t)NN * NH * 4);
  us* supb    = (us*)alloc((size_t)NN * NH * 2);
  us* hb      = (us*)alloc((size_t)NN * NH * 2);
  us* hTb     = (us*)alloc((size_t)NN * NH * 2);
  us* convWT  = (us*)alloc((size_t)7 * NH * NH * 2);
  us* gatWT   = (us*)alloc((size_t)NH * NH * 2);
  us* W1t     = (us*)alloc((size_t)64 * NH * 2);
  float* va1 = (float*)alloc(NH * 4);
  float* va2 = (float*)alloc(NH * 4);
  float* fv  = (float*)alloc(NN * 4);
  float* gv  = (float*)alloc(NN * 4);
  float* Mr  = (float*)alloc(NN * 4);
  float* Lr  = (float*)alloc(NN * 4);

  float th[7];
  for (int l = 0; l < 7; ++l) {
    float t = logf(1.5f / (float)(l + 1) + 1.f);
    th[l] = t < 1.f ? t : 1.f;
  }
  float th9 = logf(1.5f / 9.f + 1.f);

  f32_to_bf16_vec<<<(NN * (long)NN) / (4 * 256), 256, 0, stream>>>(dist, distb);
  for (int i = 0; i < 7; ++i)
    transpose_f32_bf16<<<dim3(32, 32), 256, 0, stream>>>(
        conv_W + (size_t)i * NH * NH, convWT + (size_t)i * NH * NH, NH, NH);
  transpose_f32_bf16<<<dim3(32, 32), 256, 0, stream>>>(gat_W, gatWT, NH, NH);
  transpose_f32_bf16<<<dim3(2, 32), 256, 0, stream>>>(cls1_W, W1t, NH, 64);

  fc_kernel<<<NN, 256, 0, stream>>>(x, fc_W, fc_b, h0f, hf);
  transpose_f32_bf16<<<dim3(NH / 32, NN / 32), 256, 0, stream>>>(hf, hTb, NN, NH);

  for (int l = 0; l < 7; ++l) {
    gemm_big<<<256, 512, 0, stream>>>(distb, hTb, h0f, supf, supb);
    gemm_db<1><<<512, 256, 0, stream>>>(supb, convWT + (size_t)l * NH * NH, NH,
                                        supf, hf, nullptr, hTb, th[l]);
  }

  wv_kernel<<<NH, 256, 0, stream>>>(gat_W, gat_a, va1, va2);
  fg_kernel<<<NN, 256, 0, stream>>>(hf, va1, va2, fv, gv);
  attn_ml<<<NN, 256, 0, stream>>>(adj, fv, gv, Mr, Lr);
  attn_p<<<(NN * (long)NN) / (4 * 256), 256, 0, stream>>>(adj, fv, gv, Mr, Lr, distb);

  gemm_big<<<256, 512, 0, stream>>>(distb, hTb, h0f, supf, supb);
  gemm_db<2><<<512, 256, 0, stream>>>(supb, gatWT, NH, supf, hf, hb, nullptr, th9);

  cls_gemm<<<64, 256, 0, stream>>>(hb, W1t, cls1_b, cls3_W, cls3_b, out);
}

// Round 4
// 2190.400 us; speedup vs baseline: 1.1179x; 1.1179x over previous
//
#include <hip/hip_runtime.h>
#include <math.h>

#define NN 8192
#define NH 1024

typedef __bf16 bf16x8 __attribute__((ext_vector_type(8)));
typedef float floatx4 __attribute__((ext_vector_type(4)));
typedef unsigned short us8 __attribute__((ext_vector_type(8)));
typedef unsigned short us;

__device__ __forceinline__ unsigned short f2bf(float f) {
  unsigned int u = __float_as_uint(f);
  u += 0x7fffu + ((u >> 16) & 1u);
  return (unsigned short)(u >> 16);
}

__device__ __forceinline__ void async16(const void* g, void* l) {
  __builtin_amdgcn_global_load_lds(
      (__attribute__((address_space(1))) void*)(g),
      (__attribute__((address_space(3))) void*)(l), 16, 0, 0);
}

// ===== big GEMM (K=8192, EPI0): sup = 0.3*(A@Bt^T) + 0.7*h0 =================
// 256x128 block tile, 512 threads (8 waves, 64x64 wave tile, 2 waves/SIMD),
// grid 256 (1 block/CU). BK=64: 3 stages x 48 KB = 144 KB LDS, 6 loads/stage,
// counted vmcnt(6) + ONE barrier per K-step, 128 K-steps (halved barrier
// count vs BK=32/256 steps — the rendezvous overhead was ~20% of runtime).
// Rows are 64 us = 128 B: XOR-swizzle 16B-chunk with (row&7) — source chunk
// permuted (tid&7)^((tid>>3)&7), read chunk (kk*4+q)^(fr&7); 2 lanes per
// chunk-slot => conflict-free ds_read_b128.
__global__ __launch_bounds__(512, 2)
void gemm_big(const us* __restrict__ A, const us* __restrict__ Bt,
              const float* __restrict__ aux, float* __restrict__ supf,
              us* __restrict__ supb)
{
  __shared__ __align__(16) us lsm[73728];  // 144 KB
  us* lB = lsm;            // stage s at s*8192  (16 KB/stage)
  us* lA = lsm + 24576;    // stage s at s*16384 (32 KB/stage)

  const int id = blockIdx.x;
  const int yt = id & 31;   // M-tile: ids of one stripe differ by 32 -> same XCD
  const int xt = id >> 5;

  const int tid  = threadIdx.x;
  const int lane = tid & 63;
  const int wave = tid >> 6;
  const long tileM = (long)yt * 256;
  const long tileN = (long)xt * 128;
  const int wm = (wave & 3) * 64;
  const int wn = (wave >> 2) * 64;

  // physical 16B-chunk p=(tid&7) of row r=(tid>>3)(+64l) holds logical
  // chunk p ^ (r&7) = p ^ ((tid>>3)&7)
  const int chunk8 = (tid & 7) ^ ((tid >> 3) & 7);
  const us* gA0 = A + (tileM + (tid >> 3)) * 8192L + chunk8 * 8;
  const us* gB0 = Bt + (tileN + (tid >> 3)) * 8192L + chunk8 * 8;
  const int lo = tid * 8;

  const int fr = lane & 15;
  const int q  = lane >> 4;                    // 0..3
  const int cx0 = ((q) ^ (fr & 7)) * 8;        // kk=0 swizzled us-offset
  const int cx1 = ((4 + q) ^ (fr & 7)) * 8;    // kk=1

  floatx4 zero4 = {0.f, 0.f, 0.f, 0.f};
  floatx4 acc[4][4];
#pragma unroll
  for (int i = 0; i < 4; ++i)
#pragma unroll
    for (int j = 0; j < 4; ++j) acc[i][j] = zero4;

#define STAGE_BIG(s, kf)                                                  \
  {                                                                       \
    const long ko = (long)(kf) << 6;                                      \
    async16(gA0 + ko,              lA + (s)*16384 + lo);                  \
    async16(gA0 + 64 * 8192L + ko, lA + (s)*16384 + 4096 + lo);           \
    async16(gA0 + 128 * 8192L + ko, lA + (s)*16384 + 8192 + lo);          \
    async16(gA0 + 192 * 8192L + ko, lA + (s)*16384 + 12288 + lo);         \
    async16(gB0 + ko,              lB + (s)*8192 + lo);                   \
    async16(gB0 + 64 * 8192L + ko, lB + (s)*8192 + 4096 + lo);            \
  }

#define KSTEP_BIG(s, kf)                                                  \
  {                                                                       \
    asm volatile("s_waitcnt vmcnt(6)\n\ts_barrier" ::: "memory");         \
    STAGE_BIG((((s) + 2) % 3), kf);                                       \
    bf16x8 af[2][4], bfr[2][4];                                           \
    _Pragma("unroll") for (int i = 0; i < 4; ++i) {                       \
      af[0][i] = *(const bf16x8*)&lA[(s)*16384 + (wm + 16 * i + fr) * 64 + cx0]; \
      af[1][i] = *(const bf16x8*)&lA[(s)*16384 + (wm + 16 * i + fr) * 64 + cx1]; \
    }                                                                     \
    _Pragma("unroll") for (int j = 0; j < 4; ++j) {                       \
      bfr[0][j] = *(const bf16x8*)&lB[(s)*8192 + (wn + 16 * j + fr) * 64 + cx0]; \
      bfr[1][j] = *(const bf16x8*)&lB[(s)*8192 + (wn + 16 * j + fr) * 64 + cx1]; \
    }                                                                     \
    _Pragma("unroll") for (int kk = 0; kk < 2; ++kk)                      \
      _Pragma("unroll") for (int i = 0; i < 4; ++i)                       \
        _Pragma("unroll") for (int j = 0; j < 4; ++j)                     \
            acc[i][j] = __builtin_amdgcn_mfma_f32_16x16x32_bf16(          \
                af[kk][i], bfr[kk][j], acc[i][j], 0, 0, 0);               \
  }

  // prologue: k-chunks 0,1 -> stages 0,1 (12 loads in flight per thread set)
  STAGE_BIG(0, 0)
  STAGE_BIG(1, 1)

  // 128 K-steps total; step t uses buffer t%3, prefetches chunk t+2
  for (int kt = 0; kt < 126; kt += 3) {
    KSTEP_BIG(0, kt + 2)
    KSTEP_BIG(1, kt + 3)
    KSTEP_BIG(2, kt + 4)
  }
  KSTEP_BIG(0, 127)  // t=126 (dummy re-stage of chunk 127, never read)
  KSTEP_BIG(1, 127)  // t=127
  asm volatile("s_waitcnt vmcnt(0)" ::: "memory");

  const int crow = (lane >> 4) * 4;
#pragma unroll
  for (int i = 0; i < 4; ++i)
#pragma unroll
    for (int j = 0; j < 4; ++j)
#pragma unroll
      for (int r = 0; r < 4; ++r) {
        long row = tileM + wm + 16 * i + crow + r;
        long col = tileN + wn + 16 * j + fr;
        long idx = row * NH + col;
        float s = 0.3f * acc[i][j][r] + 0.7f * aux[idx];
        supf[idx] = s;
        supb[idx] = f2bf(s);
      }
#undef STAGE_BIG
#undef KSTEP_BIG
}

// ===== small GEMM (K=1024 fixed) + epilogue =================================
// 4-stage counted vmcnt(8), single barrier per K-step (R3's extra barrier +
// setprio stripped — that wrapper cost 6% on gemm_big). 64 KB LDS, grid 512
// = 2 blocks/CU. 4 waves, 64x64 wave tile. Source-permuted chunk swizzle.
// EPI 1: o = relu(th*acc + (1-th)*aux + iof); write iof(hf), fused-T -> hTb
// EPI 2: o = elu(...);                        write iof(hf), outb(hb)
template<int EPI>
__global__ __launch_bounds__(256)
void gemm_db(const us* __restrict__ A, const us* __restrict__ Bt, int K,
             const float* __restrict__ aux, float* __restrict__ iof,
             us* __restrict__ outb, us* __restrict__ hTb, float theta)
{
  __shared__ __align__(16) us lsm[32768];  // 64 KB: 4 stages x (8KB A + 8KB B)
  us* lB = lsm;            // stage s at s*4096
  us* lA = lsm + 16384;    // stage s at s*4096

  const int id = blockIdx.x;
  const int xcd = id & 7, slot = id >> 3;
  const int xt = slot & 7;
  const int yt = xcd + 8 * (slot >> 3);

  const int tid  = threadIdx.x;
  const int lane = tid & 63;
  const int wave = tid >> 6;
  const long tileM = (long)yt * 128;
  const long tileN = (long)xt * 128;
  const int wm = (wave & 1) * 64;
  const int wn = (wave >> 1) * 64;

  const int chunk = (tid & 3) ^ ((tid >> 3) & 3);
  const us* gA0 = A + (tileM + (tid >> 2)) * (long)K + chunk * 8;
  const us* gA1 = gA0 + 64L * K;
  const us* gB0 = Bt + (tileN + (tid >> 2)) * (long)K + chunk * 8;
  const us* gB1 = gB0 + 64L * K;
  const int lo = tid * 8;

  const int fr = lane & 15;
  const int q8 = (lane >> 4) * 8;
  const int q8x = q8 ^ ((fr & 6) << 2);

  floatx4 zero4 = {0.f, 0.f, 0.f, 0.f};
  floatx4 acc[4][4];
#pragma unroll
  for (int i = 0; i < 4; ++i)
#pragma unroll
    for (int j = 0; j < 4; ++j) acc[i][j] = zero4;

#define STAGE_DB(s, kf)                                                   \
  {                                                                       \
    const int k0 = (kf) << 5;                                             \
    async16(gA0 + k0, lA + (s)*4096 + lo);                                \
    async16(gA1 + k0, lA + (s)*4096 + 2048 + lo);                         \
    async16(gB0 + k0, lB + (s)*4096 + lo);                                \
    async16(gB1 + k0, lB + (s)*4096 + 2048 + lo);                         \
  }

#define KSTEP_DB(s, kf)                                                   \
  {                                                                       \
    asm volatile("s_waitcnt vmcnt(8)\n\ts_barrier" ::: "memory");         \
    STAGE_DB((((s) + 3) & 3), kf);                                        \
    bf16x8 af[4], bfr[4];                                                 \
    _Pragma("unroll") for (int i = 0; i < 4; ++i)                         \
        af[i] = *(const bf16x8*)&lA[(s)*4096 + (wm + 16 * i + fr) * 32 + q8x]; \
    _Pragma("unroll") for (int j = 0; j < 4; ++j)                         \
        bfr[j] = *(const bf16x8*)&lB[(s)*4096 + (wn + 16 * j + fr) * 32 + q8x]; \
    _Pragma("unroll") for (int i = 0; i < 4; ++i)                         \
        _Pragma("unroll") for (int j = 0; j < 4; ++j)                     \
            acc[i][j] = __builtin_amdgcn_mfma_f32_16x16x32_bf16(          \
                af[i], bfr[j], acc[i][j], 0, 0, 0);                       \
  }

  // K = 1024: 32 K-steps. Prologue stages 0,1,2 (12 loads in flight).
  STAGE_DB(0, 0)
  STAGE_DB(1, 1)
  STAGE_DB(2, 2)

  for (int kt = 0; kt < 32; kt += 4) {
    int k3 = kt + 3; if (k3 > 31) k3 = 31;
    int k4 = kt + 4; if (k4 > 31) k4 = 31;
    int k5 = kt + 5; if (k5 > 31) k5 = 31;
    int k6 = kt + 6; if (k6 > 31) k6 = 31;
    KSTEP_DB(0, k3)
    KSTEP_DB(1, k4)
    KSTEP_DB(2, k5)
    KSTEP_DB(3, k6)
  }
  asm volatile("s_waitcnt vmcnt(0)" ::: "memory");
  __syncthreads();

  us* ldsT = lsm;  // [col][row], stride 136 (EPI 1 only)
  const int crow = (lane >> 4) * 4;
#pragma unroll
  for (int i = 0; i < 4; ++i) {
#pragma unroll
    for (int j = 0; j < 4; ++j) {
#pragma unroll
      for (int r = 0; r < 4; ++r) {
        int lr = wm + 16 * i + crow + r;
        int lc = wn + 16 * j + fr;
        long idx = (tileM + lr) * NH + tileN + lc;
        float o = theta * acc[i][j][r] + (1.f - theta) * aux[idx] + iof[idx];
        o = (EPI == 1) ? fmaxf(o, 0.f) : (o > 0.f ? o : __expf(o) - 1.f);
        iof[idx] = o;
        if (EPI == 1) ldsT[lc * 136 + lr] = f2bf(o);
        if (EPI == 2) outb[idx] = f2bf(o);
      }
    }
  }
  if (EPI == 1) {
    __syncthreads();
    int c = tid >> 1, half = tid & 1;
#pragma unroll
    for (int it = 0; it < 8; ++it) {
      int r = half * 64 + it * 8;
      us8 v = *(const us8*)&ldsT[c * 136 + r];
      *(us8*)&hTb[(tileN + c) * 8192L + tileM + r] = v;
    }
  }
#undef STAGE_DB
#undef KSTEP_DB
}

// ======== classifier head as MFMA GEMM: out = sigmoid(relu(h@W1+b1)@W3+b3) ===
__global__ __launch_bounds__(256)
void cls_gemm(const us* __restrict__ hb, const us* __restrict__ W1t,
              const float* __restrict__ b1, const float* __restrict__ W3,
              const float* __restrict__ b3, float* __restrict__ out)
{
  __shared__ __align__(16) us lA[4096];
  __shared__ __align__(16) us lB[2048];
  const int tid = threadIdx.x, lane = tid & 63, wave = tid >> 6;
  const long tileM = (long)blockIdx.x * 128;
  const us* gA0 = hb + (tileM + (tid >> 2)) * 1024L + (tid & 3) * 8;
  const us* gA1 = gA0 + 64 * 1024L;
  const us* gB0 = W1t + (tid >> 2) * 1024L + (tid & 3) * 8;
  const int fr = lane & 15, q8 = (lane >> 4) * 8;
  const int wm = wave * 32;

  floatx4 zero4 = {0.f, 0.f, 0.f, 0.f};
  floatx4 acc[2][4];
#pragma unroll
  for (int i = 0; i < 2; ++i)
#pragma unroll
    for (int j = 0; j < 4; ++j) acc[i][j] = zero4;

  for (int kt = 0; kt < 32; ++kt) {
    const int k0 = kt << 5;
    async16(gA0 + k0, lA + tid * 8);
    async16(gA1 + k0, lA + 2048 + tid * 8);
    async16(gB0 + k0, lB + tid * 8);
    __syncthreads();
    bf16x8 af[2], bfr[4];
#pragma unroll
    for (int i = 0; i < 2; ++i)
      af[i] = *(const bf16x8*)&lA[(wm + 16 * i + fr) * 32 + q8];
#pragma unroll
    for (int j = 0; j < 4; ++j)
      bfr[j] = *(const bf16x8*)&lB[(16 * j + fr) * 32 + q8];
#pragma unroll
    for (int i = 0; i < 2; ++i)
#pragma unroll
      for (int j = 0; j < 4; ++j)
        acc[i][j] = __builtin_amdgcn_mfma_f32_16x16x32_bf16(af[i], bfr[j], acc[i][j], 0, 0, 0);
    __syncthreads();
  }

  float b1v[4], w3v[4];
#pragma unroll
  for (int j = 0; j < 4; ++j) { b1v[j] = b1[16 * j + fr]; w3v[j] = W3[16 * j + fr]; }
  const float b3v = b3[0];
  const int crow = (lane >> 4) * 4;
#pragma unroll
  for (int i = 0; i < 2; ++i)
#pragma unroll
    for (int r = 0; r < 4; ++r) {
      float v = 0.f;
#pragma unroll
      for (int j = 0; j < 4; ++j)
        v += fmaxf(acc[i][j][r] + b1v[j], 0.f) * w3v[j];
      v += __shfl_xor(v, 1);
      v += __shfl_xor(v, 2);
      v += __shfl_xor(v, 4);
      v += __shfl_xor(v, 8);
      if (fr == 0)
        out[tileM + wm + 16 * i + crow + r] = 1.f / (1.f + __expf(-(v + b3v)));
    }
}

// ---------------- fp32 (R x C) -> bf16 transposed (C x R) ----------------
__global__ __launch_bounds__(256)
void transpose_f32_bf16(const float* __restrict__ src, us* __restrict__ dst,
                        int R, int C) {
  __shared__ float t[32][33];
  int tid = threadIdx.x;
  int tx = tid & 31, ty = tid >> 5;
  long r0 = (long)blockIdx.y * 32, c0 = (long)blockIdx.x * 32;
#pragma unroll
  for (int i = 0; i < 32; i += 8)
    t[ty + i][tx] = src[(r0 + ty + i) * C + c0 + tx];
  __syncthreads();
#pragma unroll
  for (int i = 0; i < 32; i += 8)
    dst[(c0 + ty + i) * R + r0 + tx] = f2bf(t[tx][ty + i]);
}

// ---------------- fp32 -> bf16 elementwise (dist) ----------------
__global__ __launch_bounds__(256)
void f32_to_bf16_vec(const float* __restrict__ s, us* __restrict__ d) {
  long i = (blockIdx.x * 256L + threadIdx.x) * 4;
  float4 v = *(const float4*)(s + i);
  *(ushort4*)(d + i) = make_ushort4(f2bf(v.x), f2bf(v.y), f2bf(v.z), f2bf(v.w));
}

// ---------------- h0 = relu(x @ fc_W + fc_b) ----------------
__global__ __launch_bounds__(256)
void fc_kernel(const float* __restrict__ x, const float* __restrict__ W,
               const float* __restrict__ b, float* __restrict__ h0f,
               float* __restrict__ hf) {
  __shared__ float xs[64];
  int row = blockIdx.x, tid = threadIdx.x;
  if (tid < 63) xs[tid] = x[row * 63 + tid];
  __syncthreads();
#pragma unroll
  for (int q = 0; q < 4; ++q) {
    int c = tid + q * 256;
    float s = b[c];
    for (int k = 0; k < 63; ++k) s += xs[k] * W[k * NH + c];
    s = fmaxf(s, 0.f);
    long idx = (long)row * NH + c;
    h0f[idx] = s;
    hf[idx] = s;
  }
}

// ---------------- va1 = gat_W @ a1, va2 = gat_W @ a2 ----------------
__global__ __launch_bounds__(256)
void wv_kernel(const float* __restrict__ W, const float* __restrict__ a,
               float* __restrict__ va1, float* __restrict__ va2) {
  int k = blockIdx.x, tid = threadIdx.x;
  float s1 = 0.f, s2 = 0.f;
  for (int n = tid; n < NH; n += 256) {
    float w = W[(long)k * NH + n];
    s1 += w * a[n];
    s2 += w * a[NH + n];
  }
#pragma unroll
  for (int o = 32; o; o >>= 1) { s1 += __shfl_down(s1, o); s2 += __shfl_down(s2, o); }
  __shared__ float r1[4], r2[4];
  int wave = tid >> 6;
  if ((tid & 63) == 0) { r1[wave] = s1; r2[wave] = s2; }
  __syncthreads();
  if (tid == 0) {
    va1[k] = r1[0] + r1[1] + r1[2] + r1[3];
    va2[k] = r2[0] + r2[1] + r2[2] + r2[3];
  }
}

// ---------------- f = h @ va1, g = h @ va2 ----------------
__global__ __launch_bounds__(256)
void fg_kernel(const float* __restrict__ h, const float* __restrict__ va1,
               const float* __restrict__ va2, float* __restrict__ fv,
               float* __restrict__ gv) {
  int row = blockIdx.x, tid = threadIdx.x;
  float s1 = 0.f, s2 = 0.f;
  for (int k = tid; k < NH; k += 256) {
    float v = h[(long)row * NH + k];
    s1 += v * va1[k];
    s2 += v * va2[k];
  }
#pragma unroll
  for (int o = 32; o; o >>= 1) { s1 += __shfl_down(s1, o); s2 += __shfl_down(s2, o); }
  __shared__ float r1[4], r2[4];
  int wave = tid >> 6;
  if ((tid & 63) == 0) { r1[wave] = s1; r2[wave] = s2; }
  __syncthreads();
  if (tid == 0) {
    fv[row] = r1[0] + r1[1] + r1[2] + r1[3];
    gv[row] = r2[0] + r2[1] + r2[2] + r2[3];
  }
}

// ---------------- attention pass 1: per-row max & denom ----------------
__global__ __launch_bounds__(256)
void attn_ml(const int* __restrict__ adj, const float* __restrict__ f,
             const float* __restrict__ g, float* __restrict__ Mr,
             float* __restrict__ Lr) {
  const int row = blockIdx.x, tid = threadIdx.x;
  const float fi = f[row];
  const int4* arow = (const int4*)(adj + (long)row * NN);
  float m = -3.0e38f, s = 0.f;
  for (int c = tid; c < NN / 4; c += 256) {
    int4 a = arow[c];
    float4 gg = *(const float4*)(g + c * 4);
#pragma unroll
    for (int t = 0; t < 4; ++t) {
      int av = (t == 0) ? a.x : (t == 1) ? a.y : (t == 2) ? a.z : a.w;
      float gvv = (t == 0) ? gg.x : (t == 1) ? gg.y : (t == 2) ? gg.z : gg.w;
      if (av > 0) {
        float e = fi + gvv;
        e = e > 0.f ? e : 0.2f * e;
        if (e > m) { s = s * __expf(m - e) + 1.f; m = e; }
        else s += __expf(e - m);
      }
    }
  }
#pragma unroll
  for (int o = 32; o; o >>= 1) {
    float m2 = __shfl_down(m, o), s2 = __shfl_down(s, o);
    float mn = fmaxf(m, m2);
    s = s * __expf(m - mn) + s2 * __expf(m2 - mn);
    m = mn;
  }
  __shared__ float ms[4], ss[4];
  int wave = tid >> 6;
  if ((tid & 63) == 0) { ms[wave] = m; ss[wave] = s; }
  __syncthreads();
  if (tid == 0) {
    float mm = ms[0], sv = ss[0];
    for (int w = 1; w < 4; ++w) {
      float mn = fmaxf(mm, ms[w]);
      sv = sv * __expf(mm - mn) + ss[w] * __expf(ms[w] - mn);
      mm = mn;
    }
    Mr[row] = mm;
    Lr[row] = sv;
  }
}

// ---------------- attention pass 2: P (bf16) ----------------
__global__ __launch_bounds__(256)
void attn_p(const int* __restrict__ adj, const float* __restrict__ f,
            const float* __restrict__ g, const float* __restrict__ Mr,
            const float* __restrict__ Lr, us* __restrict__ P) {
  long gid = blockIdx.x * 256L + threadIdx.x;
  int row = (int)(gid >> 11);
  int jc = (int)(gid & 2047) * 4;
  float fi = f[row], m = Mr[row], l = Lr[row];
  bool uni = !(l > 0.f);
  float inv = uni ? 0.f : 1.f / l;
  int4 a = *(const int4*)(adj + ((long)row << 13) + jc);
  float4 gg = *(const float4*)(g + jc);
  float p[4];
#pragma unroll
  for (int t = 0; t < 4; ++t) {
    int av = (t == 0) ? a.x : (t == 1) ? a.y : (t == 2) ? a.z : a.w;
    float gvv = (t == 0) ? gg.x : (t == 1) ? gg.y : (t == 2) ? gg.z : gg.w;
    float e = fi + gvv;
    e = e > 0.f ? e : 0.2f * e;
    float pv = (av > 0) ? __expf(e - m) * inv : 0.f;
    if (uni) pv = 1.f / (float)NN;
    p[t] = pv;
  }
  *(ushort4*)(P + ((long)row << 13) + jc) =
      make_ushort4(f2bf(p[0]), f2bf(p[1]), f2bf(p[2]), f2bf(p[3]));
}

extern "C" void kernel_launch(void* const* d_in, const int* in_sizes, int n_in,
                              void* d_out, int out_size, void* d_ws, size_t ws_size,
                              hipStream_t stream) {
  const float* x      = (const float*)d_in[0];
  const float* dist   = (const float*)d_in[1];
  const int*   adj    = (const int*)d_in[2];
  const float* fc_W   = (const float*)d_in[3];
  const float* fc_b   = (const float*)d_in[4];
  const float* conv_W = (const float*)d_in[5];
  const float* gat_W  = (const float*)d_in[6];
  const float* gat_a  = (const float*)d_in[7];
  const float* cls1_W = (const float*)d_in[8];
  const float* cls1_b = (const float*)d_in[9];
  const float* cls3_W = (const float*)d_in[10];
  const float* cls3_b = (const float*)d_in[11];
  float* out = (float*)d_out;

  char* p = (char*)d_ws;
  auto alloc = [&](size_t bytes) {
    char* r = p;
    p += (bytes + 255) & ~(size_t)255;
    return r;
  };
  us* distb   = (us*)alloc((size_t)NN * NN * 2);
  float* h0f  = (float*)alloc((size_t)NN * NH * 4);
  float* hf   = (float*)alloc((size_t)NN * NH * 4);
  float* supf = (float*)alloc((size_t)NN * NH * 4);
  us* supb    = (us*)alloc((size_t)NN * NH * 2);
  us* hb      = (us*)alloc((size_t)NN * NH * 2);
  us* hTb     = (us*)alloc((size_t)NN * NH * 2);
  us* convWT  = (us*)alloc((size_t)7 * NH * NH * 2);
  us* gatWT   = (us*)alloc((size_t)NH * NH * 2);
  us* W1t     = (us*)alloc((size_t)64 * NH * 2);
  float* va1 = (float*)alloc(NH * 4);
  float* va2 = (float*)alloc(NH * 4);
  float* fv  = (float*)alloc(NN * 4);
  float* gv  = (float*)alloc(NN * 4);
  float* Mr  = (float*)alloc(NN * 4);
  float* Lr  = (float*)alloc(NN * 4);

  float th[7];
  for (int l = 0; l < 7; ++l) {
    float t = logf(1.5f / (float)(l + 1) + 1.f);
    th[l] = t < 1.f ? t : 1.f;
  }
  float th9 = logf(1.5f / 9.f + 1.f);

  f32_to_bf16_vec<<<(NN * (long)NN) / (4 * 256), 256, 0, stream>>>(dist, distb);
  for (int i = 0; i < 7; ++i)
    transpose_f32_bf16<<<dim3(32, 32), 256, 0, stream>>>(
        conv_W + (size_t)i * NH * NH, convWT + (size_t)i * NH * NH, NH, NH);
  transpose_f32_bf16<<<dim3(32, 32), 256, 0, stream>>>(gat_W, gatWT, NH, NH);
  transpose_f32_bf16<<<dim3(2, 32), 256, 0, stream>>>(cls1_W, W1t, NH, 64);

  fc_kernel<<<NN, 256, 0, stream>>>(x, fc_W, fc_b, h0f, hf);
  transpose_f32_bf16<<<dim3(NH / 32, NN / 32), 256, 0, stream>>>(hf, hTb, NN, NH);

  for (int l = 0; l < 7; ++l) {
    gemm_big<<<256, 512, 0, stream>>>(distb, hTb, h0f, supf, supb);
    gemm_db<1><<<512, 256, 0, stream>>>(supb, convWT + (size_t)l * NH * NH, NH,
                                        supf, hf, nullptr, hTb, th[l]);
  }

  wv_kernel<<<NH, 256, 0, stream>>>(gat_W, gat_a, va1, va2);
  fg_kernel<<<NN, 256, 0, stream>>>(hf, va1, va2, fv, gv);
  attn_ml<<<NN, 256, 0, stream>>>(adj, fv, gv, Mr, Lr);
  attn_p<<<(NN * (long)NN) / (4 * 256), 256, 0, stream>>>(adj, fv, gv, Mr, Lr, distb);

  gemm_big<<<256, 512, 0, stream>>>(distb, hTb, h0f, supf, supb);
  gemm_db<2><<<512, 256, 0, stream>>>(supb, gatWT, NH, supf, hf, hb, nullptr, th9);

  cls_gemm<<<64, 256, 0, stream>>>(hb, W1t, cls1_b, cls3_W, cls3_b, out);
}

// Round 5
// 2178.162 us; speedup vs baseline: 1.1242x; 1.0056x over previous
//
#include <hip/hip_runtime.h>
#include <math.h>

#define NN 8192
#define NH 1024

typedef __bf16 bf16x8 __attribute__((ext_vector_type(8)));
typedef float floatx4 __attribute__((ext_vector_type(4)));
typedef unsigned short us8 __attribute__((ext_vector_type(8)));
typedef unsigned short us;

__device__ __forceinline__ unsigned short f2bf(float f) {
  unsigned int u = __float_as_uint(f);
  u += 0x7fffu + ((u >> 16) & 1u);
  return (unsigned short)(u >> 16);
}

__device__ __forceinline__ void async16(const void* g, void* l) {
  __builtin_amdgcn_global_load_lds(
      (__attribute__((address_space(1))) void*)(g),
      (__attribute__((address_space(3))) void*)(l), 16, 0, 0);
}

// ===== big GEMM (K=8192, EPI0): sup = 0.3*(A@Bt^T) + 0.7*h0 =================
// 256x128 block tile, 512 threads (8 waves, 64x64 wave tile, 2 waves/SIMD),
// grid 256 (1 block/CU). BK=64: 3 stages x 48 KB = 144 KB LDS, 6 loads/stage,
// counted vmcnt(6) + ONE barrier per K-step, 128 K-steps. At 898 TF this is
// the m157-structure ceiling (matches guide); further gains need the full
// 8-phase fine-interleave template (not reconstructible headlessly).
// Rows are 64 us = 128 B: XOR-swizzle 16B-chunk with (row&7) — source chunk
// permuted (tid&7)^((tid>>3)&7), read chunk (kk*4+q)^(fr&7); conflict-free.
__global__ __launch_bounds__(512, 2)
void gemm_big(const us* __restrict__ A, const us* __restrict__ Bt,
              const float* __restrict__ aux, float* __restrict__ supf,
              us* __restrict__ supb)
{
  __shared__ __align__(16) us lsm[73728];  // 144 KB
  us* lB = lsm;            // stage s at s*8192  (16 KB/stage)
  us* lA = lsm + 24576;    // stage s at s*16384 (32 KB/stage)

  const int id = blockIdx.x;
  const int yt = id & 31;   // M-tile: ids of one stripe differ by 32 -> same XCD
  const int xt = id >> 5;

  const int tid  = threadIdx.x;
  const int lane = tid & 63;
  const int wave = tid >> 6;
  const long tileM = (long)yt * 256;
  const long tileN = (long)xt * 128;
  const int wm = (wave & 3) * 64;
  const int wn = (wave >> 2) * 64;

  // physical 16B-chunk p=(tid&7) of row r=(tid>>3)(+64l) holds logical
  // chunk p ^ (r&7) = p ^ ((tid>>3)&7)
  const int chunk8 = (tid & 7) ^ ((tid >> 3) & 7);
  const us* gA0 = A + (tileM + (tid >> 3)) * 8192L + chunk8 * 8;
  const us* gB0 = Bt + (tileN + (tid >> 3)) * 8192L + chunk8 * 8;
  const int lo = tid * 8;

  const int fr = lane & 15;
  const int q  = lane >> 4;                    // 0..3
  const int cx0 = ((q) ^ (fr & 7)) * 8;        // kk=0 swizzled us-offset
  const int cx1 = ((4 + q) ^ (fr & 7)) * 8;    // kk=1

  floatx4 zero4 = {0.f, 0.f, 0.f, 0.f};
  floatx4 acc[4][4];
#pragma unroll
  for (int i = 0; i < 4; ++i)
#pragma unroll
    for (int j = 0; j < 4; ++j) acc[i][j] = zero4;

#define STAGE_BIG(s, kf)                                                  \
  {                                                                       \
    const long ko = (long)(kf) << 6;                                      \
    async16(gA0 + ko,              lA + (s)*16384 + lo);                  \
    async16(gA0 + 64 * 8192L + ko, lA + (s)*16384 + 4096 + lo);           \
    async16(gA0 + 128 * 8192L + ko, lA + (s)*16384 + 8192 + lo);          \
    async16(gA0 + 192 * 8192L + ko, lA + (s)*16384 + 12288 + lo);         \
    async16(gB0 + ko,              lB + (s)*8192 + lo);                   \
    async16(gB0 + 64 * 8192L + ko, lB + (s)*8192 + 4096 + lo);            \
  }

#define KSTEP_BIG(s, kf)                                                  \
  {                                                                       \
    asm volatile("s_waitcnt vmcnt(6)\n\ts_barrier" ::: "memory");         \
    STAGE_BIG((((s) + 2) % 3), kf);                                       \
    bf16x8 af[2][4], bfr[2][4];                                           \
    _Pragma("unroll") for (int i = 0; i < 4; ++i) {                       \
      af[0][i] = *(const bf16x8*)&lA[(s)*16384 + (wm + 16 * i + fr) * 64 + cx0]; \
      af[1][i] = *(const bf16x8*)&lA[(s)*16384 + (wm + 16 * i + fr) * 64 + cx1]; \
    }                                                                     \
    _Pragma("unroll") for (int j = 0; j < 4; ++j) {                       \
      bfr[0][j] = *(const bf16x8*)&lB[(s)*8192 + (wn + 16 * j + fr) * 64 + cx0]; \
      bfr[1][j] = *(const bf16x8*)&lB[(s)*8192 + (wn + 16 * j + fr) * 64 + cx1]; \
    }                                                                     \
    _Pragma("unroll") for (int kk = 0; kk < 2; ++kk)                      \
      _Pragma("unroll") for (int i = 0; i < 4; ++i)                       \
        _Pragma("unroll") for (int j = 0; j < 4; ++j)                     \
            acc[i][j] = __builtin_amdgcn_mfma_f32_16x16x32_bf16(          \
                af[kk][i], bfr[kk][j], acc[i][j], 0, 0, 0);               \
  }

  // prologue: k-chunks 0,1 -> stages 0,1 (12 loads in flight per thread set)
  STAGE_BIG(0, 0)
  STAGE_BIG(1, 1)

  // 128 K-steps total; step t uses buffer t%3, prefetches chunk t+2
  for (int kt = 0; kt < 126; kt += 3) {
    KSTEP_BIG(0, kt + 2)
    KSTEP_BIG(1, kt + 3)
    KSTEP_BIG(2, kt + 4)
  }
  KSTEP_BIG(0, 127)  // t=126 (dummy re-stage of chunk 127, never read)
  KSTEP_BIG(1, 127)  // t=127
  asm volatile("s_waitcnt vmcnt(0)" ::: "memory");

  const int crow = (lane >> 4) * 4;
#pragma unroll
  for (int i = 0; i < 4; ++i)
#pragma unroll
    for (int j = 0; j < 4; ++j)
#pragma unroll
      for (int r = 0; r < 4; ++r) {
        long row = tileM + wm + 16 * i + crow + r;
        long col = tileN + wn + 16 * j + fr;
        long idx = row * NH + col;
        float s = 0.3f * acc[i][j][r] + 0.7f * aux[idx];
        supf[idx] = s;
        supb[idx] = f2bf(s);
      }
#undef STAGE_BIG
#undef KSTEP_BIG
}

// ===== small GEMM (K=1024 fixed) + epilogue =================================
// 4-stage counted vmcnt(8), single barrier per K-step. 64 KB LDS, grid 512
// = 2 blocks/CU. 4 waves, 64x64 wave tile. Source-permuted chunk swizzle.
// EPI 1: o = relu(th*acc + (1-th)*aux + iof); write iof(hf), fused-T -> hTb
//        (hTb write remapped: 16 lanes per column -> 256B contiguous runs,
//         was 64 scattered 16B transactions per wave)
// EPI 2: o = elu(...);                        write iof(hf), outb(hb)
template<int EPI>
__global__ __launch_bounds__(256)
void gemm_db(const us* __restrict__ A, const us* __restrict__ Bt, int K,
             const float* __restrict__ aux, float* __restrict__ iof,
             us* __restrict__ outb, us* __restrict__ hTb, float theta)
{
  __shared__ __align__(16) us lsm[32768];  // 64 KB: 4 stages x (8KB A + 8KB B)
  us* lB = lsm;            // stage s at s*4096
  us* lA = lsm + 16384;    // stage s at s*4096

  const int id = blockIdx.x;
  const int xcd = id & 7, slot = id >> 3;
  const int xt = slot & 7;
  const int yt = xcd + 8 * (slot >> 3);

  const int tid  = threadIdx.x;
  const int lane = tid & 63;
  const int wave = tid >> 6;
  const long tileM = (long)yt * 128;
  const long tileN = (long)xt * 128;
  const int wm = (wave & 1) * 64;
  const int wn = (wave >> 1) * 64;

  const int chunk = (tid & 3) ^ ((tid >> 3) & 3);
  const us* gA0 = A + (tileM + (tid >> 2)) * (long)K + chunk * 8;
  const us* gA1 = gA0 + 64L * K;
  const us* gB0 = Bt + (tileN + (tid >> 2)) * (long)K + chunk * 8;
  const us* gB1 = gB0 + 64L * K;
  const int lo = tid * 8;

  const int fr = lane & 15;
  const int q8 = (lane >> 4) * 8;
  const int q8x = q8 ^ ((fr & 6) << 2);

  floatx4 zero4 = {0.f, 0.f, 0.f, 0.f};
  floatx4 acc[4][4];
#pragma unroll
  for (int i = 0; i < 4; ++i)
#pragma unroll
    for (int j = 0; j < 4; ++j) acc[i][j] = zero4;

#define STAGE_DB(s, kf)                                                   \
  {                                                                       \
    const int k0 = (kf) << 5;                                             \
    async16(gA0 + k0, lA + (s)*4096 + lo);                                \
    async16(gA1 + k0, lA + (s)*4096 + 2048 + lo);                         \
    async16(gB0 + k0, lB + (s)*4096 + lo);                                \
    async16(gB1 + k0, lB + (s)*4096 + 2048 + lo);                        \
  }

#define KSTEP_DB(s, kf)                                                   \
  {                                                                       \
    asm volatile("s_waitcnt vmcnt(8)\n\ts_barrier" ::: "memory");         \
    STAGE_DB((((s) + 3) & 3), kf);                                        \
    bf16x8 af[4], bfr[4];                                                 \
    _Pragma("unroll") for (int i = 0; i < 4; ++i)                         \
        af[i] = *(const bf16x8*)&lA[(s)*4096 + (wm + 16 * i + fr) * 32 + q8x]; \
    _Pragma("unroll") for (int j = 0; j < 4; ++j)                         \
        bfr[j] = *(const bf16x8*)&lB[(s)*4096 + (wn + 16 * j + fr) * 32 + q8x]; \
    _Pragma("unroll") for (int i = 0; i < 4; ++i)                         \
        _Pragma("unroll") for (int j = 0; j < 4; ++j)                     \
            acc[i][j] = __builtin_amdgcn_mfma_f32_16x16x32_bf16(          \
                af[i], bfr[j], acc[i][j], 0, 0, 0);                       \
  }

  // K = 1024: 32 K-steps. Prologue stages 0,1,2 (12 loads in flight).
  STAGE_DB(0, 0)
  STAGE_DB(1, 1)
  STAGE_DB(2, 2)

  for (int kt = 0; kt < 32; kt += 4) {
    int k3 = kt + 3; if (k3 > 31) k3 = 31;
    int k4 = kt + 4; if (k4 > 31) k4 = 31;
    int k5 = kt + 5; if (k5 > 31) k5 = 31;
    int k6 = kt + 6; if (k6 > 31) k6 = 31;
    KSTEP_DB(0, k3)
    KSTEP_DB(1, k4)
    KSTEP_DB(2, k5)
    KSTEP_DB(3, k6)
  }
  asm volatile("s_waitcnt vmcnt(0)" ::: "memory");
  __syncthreads();

  us* ldsT = lsm;  // [col][row], stride 136 (EPI 1 only)
  const int crow = (lane >> 4) * 4;
#pragma unroll
  for (int i = 0; i < 4; ++i) {
#pragma unroll
    for (int j = 0; j < 4; ++j) {
#pragma unroll
      for (int r = 0; r < 4; ++r) {
        int lr = wm + 16 * i + crow + r;
        int lc = wn + 16 * j + fr;
        long idx = (tileM + lr) * NH + tileN + lc;
        float o = theta * acc[i][j][r] + (1.f - theta) * aux[idx] + iof[idx];
        o = (EPI == 1) ? fmaxf(o, 0.f) : (o > 0.f ? o : __expf(o) - 1.f);
        iof[idx] = o;
        if (EPI == 1) ldsT[lc * 136 + lr] = f2bf(o);
        if (EPI == 2) outb[idx] = f2bf(o);
      }
    }
  }
  if (EPI == 1) {
    __syncthreads();
    // coalesced transpose-out: 16 lanes own one column (128 rows = 16 us8),
    // adjacent lanes write adjacent 16B -> 256B contiguous runs.
    int ch = tid & 15;          // row-chunk within column
    int c0 = tid >> 4;          // column group base (16 cols per iteration)
#pragma unroll
    for (int it = 0; it < 8; ++it) {
      int c = c0 + it * 16;
      us8 v = *(const us8*)&ldsT[c * 136 + ch * 8];
      *(us8*)&hTb[(tileN + c) * 8192L + tileM + ch * 8] = v;
    }
  }
#undef STAGE_DB
#undef KSTEP_DB
}

// ======== classifier head as MFMA GEMM: out = sigmoid(relu(h@W1+b1)@W3+b3) ===
__global__ __launch_bounds__(256)
void cls_gemm(const us* __restrict__ hb, const us* __restrict__ W1t,
              const float* __restrict__ b1, const float* __restrict__ W3,
              const float* __restrict__ b3, float* __restrict__ out)
{
  __shared__ __align__(16) us lA[4096];
  __shared__ __align__(16) us lB[2048];
  const int tid = threadIdx.x, lane = tid & 63, wave = tid >> 6;
  const long tileM = (long)blockIdx.x * 128;
  const us* gA0 = hb + (tileM + (tid >> 2)) * 1024L + (tid & 3) * 8;
  const us* gA1 = gA0 + 64 * 1024L;
  const us* gB0 = W1t + (tid >> 2) * 1024L + (tid & 3) * 8;
  const int fr = lane & 15, q8 = (lane >> 4) * 8;
  const int wm = wave * 32;

  floatx4 zero4 = {0.f, 0.f, 0.f, 0.f};
  floatx4 acc[2][4];
#pragma unroll
  for (int i = 0; i < 2; ++i)
#pragma unroll
    for (int j = 0; j < 4; ++j) acc[i][j] = zero4;

  for (int kt = 0; kt < 32; ++kt) {
    const int k0 = kt << 5;
    async16(gA0 + k0, lA + tid * 8);
    async16(gA1 + k0, lA + 2048 + tid * 8);
    async16(gB0 + k0, lB + tid * 8);
    __syncthreads();
    bf16x8 af[2], bfr[4];
#pragma unroll
    for (int i = 0; i < 2; ++i)
      af[i] = *(const bf16x8*)&lA[(wm + 16 * i + fr) * 32 + q8];
#pragma unroll
    for (int j = 0; j < 4; ++j)
      bfr[j] = *(const bf16x8*)&lB[(16 * j + fr) * 32 + q8];
#pragma unroll
    for (int i = 0; i < 2; ++i)
#pragma unroll
      for (int j = 0; j < 4; ++j)
        acc[i][j] = __builtin_amdgcn_mfma_f32_16x16x32_bf16(af[i], bfr[j], acc[i][j], 0, 0, 0);
    __syncthreads();
  }

  float b1v[4], w3v[4];
#pragma unroll
  for (int j = 0; j < 4; ++j) { b1v[j] = b1[16 * j + fr]; w3v[j] = W3[16 * j + fr]; }
  const float b3v = b3[0];
  const int crow = (lane >> 4) * 4;
#pragma unroll
  for (int i = 0; i < 2; ++i)
#pragma unroll
    for (int r = 0; r < 4; ++r) {
      float v = 0.f;
#pragma unroll
      for (int j = 0; j < 4; ++j)
        v += fmaxf(acc[i][j][r] + b1v[j], 0.f) * w3v[j];
      v += __shfl_xor(v, 1);
      v += __shfl_xor(v, 2);
      v += __shfl_xor(v, 4);
      v += __shfl_xor(v, 8);
      if (fr == 0)
        out[tileM + wm + 16 * i + crow + r] = 1.f / (1.f + __expf(-(v + b3v)));
    }
}

// ---------------- fp32 (R x C) -> bf16 transposed (C x R) ----------------
__global__ __launch_bounds__(256)
void transpose_f32_bf16(const float* __restrict__ src, us* __restrict__ dst,
                        int R, int C) {
  __shared__ float t[32][33];
  int tid = threadIdx.x;
  int tx = tid & 31, ty = tid >> 5;
  long r0 = (long)blockIdx.y * 32, c0 = (long)blockIdx.x * 32;
#pragma unroll
  for (int i = 0; i < 32; i += 8)
    t[ty + i][tx] = src[(r0 + ty + i) * C + c0 + tx];
  __syncthreads();
#pragma unroll
  for (int i = 0; i < 32; i += 8)
    dst[(c0 + ty + i) * R + r0 + tx] = f2bf(t[tx][ty + i]);
}

// ---------------- fp32 -> bf16 elementwise (dist) ----------------
__global__ __launch_bounds__(256)
void f32_to_bf16_vec(const float* __restrict__ s, us* __restrict__ d) {
  long i = (blockIdx.x * 256L + threadIdx.x) * 4;
  float4 v = *(const float4*)(s + i);
  *(ushort4*)(d + i) = make_ushort4(f2bf(v.x), f2bf(v.y), f2bf(v.z), f2bf(v.w));
}

// ---------------- h0 = relu(x @ fc_W + fc_b) ----------------
__global__ __launch_bounds__(256)
void fc_kernel(const float* __restrict__ x, const float* __restrict__ W,
               const float* __restrict__ b, float* __restrict__ h0f,
               float* __restrict__ hf) {
  __shared__ float xs[64];
  int row = blockIdx.x, tid = threadIdx.x;
  if (tid < 63) xs[tid] = x[row * 63 + tid];
  __syncthreads();
#pragma unroll
  for (int q = 0; q < 4; ++q) {
    int c = tid + q * 256;
    float s = b[c];
    for (int k = 0; k < 63; ++k) s += xs[k] * W[k * NH + c];
    s = fmaxf(s, 0.f);
    long idx = (long)row * NH + c;
    h0f[idx] = s;
    hf[idx] = s;
  }
}

// ---------------- va1 = gat_W @ a1, va2 = gat_W @ a2 ----------------
__global__ __launch_bounds__(256)
void wv_kernel(const float* __restrict__ W, const float* __restrict__ a,
               float* __restrict__ va1, float* __restrict__ va2) {
  int k = blockIdx.x, tid = threadIdx.x;
  float s1 = 0.f, s2 = 0.f;
  for (int n = tid; n < NH; n += 256) {
    float w = W[(long)k * NH + n];
    s1 += w * a[n];
    s2 += w * a[NH + n];
  }
#pragma unroll
  for (int o = 32; o; o >>= 1) { s1 += __shfl_down(s1, o); s2 += __shfl_down(s2, o); }
  __shared__ float r1[4], r2[4];
  int wave = tid >> 6;
  if ((tid & 63) == 0) { r1[wave] = s1; r2[wave] = s2; }
  __syncthreads();
  if (tid == 0) {
    va1[k] = r1[0] + r1[1] + r1[2] + r1[3];
    va2[k] = r2[0] + r2[1] + r2[2] + r2[3];
  }
}

// ---------------- f = h @ va1, g = h @ va2 ----------------
__global__ __launch_bounds__(256)
void fg_kernel(const float* __restrict__ h, const float* __restrict__ va1,
               const float* __restrict__ va2, float* __restrict__ fv,
               float* __restrict__ gv) {
  int row = blockIdx.x, tid = threadIdx.x;
  float s1 = 0.f, s2 = 0.f;
  for (int k = tid; k < NH; k += 256) {
    float v = h[(long)row * NH + k];
    s1 += v * va1[k];
    s2 += v * va2[k];
  }
#pragma unroll
  for (int o = 32; o; o >>= 1) { s1 += __shfl_down(s1, o); s2 += __shfl_down(s2, o); }
  __shared__ float r1[4], r2[4];
  int wave = tid >> 6;
  if ((tid & 63) == 0) { r1[wave] = s1; r2[wave] = s2; }
  __syncthreads();
  if (tid == 0) {
    fv[row] = r1[0] + r1[1] + r1[2] + r1[3];
    gv[row] = r2[0] + r2[1] + r2[2] + r2[3];
  }
}

// ---------------- fused attention: max/denom + P in one pass ----------------
// Block per row. Pass 1 reads the 32KB adj row from HBM (online m,l);
// block-reduce + broadcast; pass 2 re-reads the SAME row from L2 (hot) and
// writes P. Saves the full 256MB second HBM sweep of the old 2-kernel split.
__global__ __launch_bounds__(256)
void attn_fused(const int* __restrict__ adj, const float* __restrict__ f,
                const float* __restrict__ g, us* __restrict__ P) {
  const int row = blockIdx.x, tid = threadIdx.x;
  const float fi = f[row];
  const int4* arow = (const int4*)(adj + (long)row * NN);
  float m = -3.0e38f, s = 0.f;
  for (int c = tid; c < NN / 4; c += 256) {
    int4 a = arow[c];
    float4 gg = *(const float4*)(g + c * 4);
#pragma unroll
    for (int t = 0; t < 4; ++t) {
      int av = (t == 0) ? a.x : (t == 1) ? a.y : (t == 2) ? a.z : a.w;
      float gvv = (t == 0) ? gg.x : (t == 1) ? gg.y : (t == 2) ? gg.z : gg.w;
      if (av > 0) {
        float e = fi + gvv;
        e = e > 0.f ? e : 0.2f * e;
        if (e > m) { s = s * __expf(m - e) + 1.f; m = e; }
        else s += __expf(e - m);
      }
    }
  }
#pragma unroll
  for (int o = 32; o; o >>= 1) {
    float m2 = __shfl_down(m, o), s2 = __shfl_down(s, o);
    float mn = fmaxf(m, m2);
    s = s * __expf(m - mn) + s2 * __expf(m2 - mn);
    m = mn;
  }
  __shared__ float ms[4], ss[4], bcast[2];
  int wave = tid >> 6;
  if ((tid & 63) == 0) { ms[wave] = m; ss[wave] = s; }
  __syncthreads();
  if (tid == 0) {
    float mm = ms[0], sv = ss[0];
    for (int w = 1; w < 4; ++w) {
      float mn = fmaxf(mm, ms[w]);
      sv = sv * __expf(mm - mn) + ss[w] * __expf(ms[w] - mn);
      mm = mn;
    }
    bcast[0] = mm;
    bcast[1] = sv;
  }
  __syncthreads();
  const float M = bcast[0], L = bcast[1];
  const bool uni = !(L > 0.f);
  const float inv = uni ? 0.f : 1.f / L;
  for (int c = tid; c < NN / 4; c += 256) {
    int4 a = arow[c];  // L2-hit: same row read us ago
    float4 gg = *(const float4*)(g + c * 4);
    float p[4];
#pragma unroll
    for (int t = 0; t < 4; ++t) {
      int av = (t == 0) ? a.x : (t == 1) ? a.y : (t == 2) ? a.z : a.w;
      float gvv = (t == 0) ? gg.x : (t == 1) ? gg.y : (t == 2) ? gg.z : gg.w;
      float e = fi + gvv;
      e = e > 0.f ? e : 0.2f * e;
      float pv = (av > 0) ? __expf(e - M) * inv : 0.f;
      if (uni) pv = 1.f / (float)NN;
      p[t] = pv;
    }
    *(ushort4*)(P + ((long)row << 13) + c * 4) =
        make_ushort4(f2bf(p[0]), f2bf(p[1]), f2bf(p[2]), f2bf(p[3]));
  }
}

extern "C" void kernel_launch(void* const* d_in, const int* in_sizes, int n_in,
                              void* d_out, int out_size, void* d_ws, size_t ws_size,
                              hipStream_t stream) {
  const float* x      = (const float*)d_in[0];
  const float* dist   = (const float*)d_in[1];
  const int*   adj    = (const int*)d_in[2];
  const float* fc_W   = (const float*)d_in[3];
  const float* fc_b   = (const float*)d_in[4];
  const float* conv_W = (const float*)d_in[5];
  const float* gat_W  = (const float*)d_in[6];
  const float* gat_a  = (const float*)d_in[7];
  const float* cls1_W = (const float*)d_in[8];
  const float* cls1_b = (const float*)d_in[9];
  const float* cls3_W = (const float*)d_in[10];
  const float* cls3_b = (const float*)d_in[11];
  float* out = (float*)d_out;

  char* p = (char*)d_ws;
  auto alloc = [&](size_t bytes) {
    char* r = p;
    p += (bytes + 255) & ~(size_t)255;
    return r;
  };
  us* distb   = (us*)alloc((size_t)NN * NN * 2);
  float* h0f  = (float*)alloc((size_t)NN * NH * 4);
  float* hf   = (float*)alloc((size_t)NN * NH * 4);
  float* supf = (float*)alloc((size_t)NN * NH * 4);
  us* supb    = (us*)alloc((size_t)NN * NH * 2);
  us* hb      = (us*)alloc((size_t)NN * NH * 2);
  us* hTb     = (us*)alloc((size_t)NN * NH * 2);
  us* convWT  = (us*)alloc((size_t)7 * NH * NH * 2);
  us* gatWT   = (us*)alloc((size_t)NH * NH * 2);
  us* W1t     = (us*)alloc((size_t)64 * NH * 2);
  float* va1 = (float*)alloc(NH * 4);
  float* va2 = (float*)alloc(NH * 4);
  float* fv  = (float*)alloc(NN * 4);
  float* gv  = (float*)alloc(NN * 4);

  float th[7];
  for (int l = 0; l < 7; ++l) {
    float t = logf(1.5f / (float)(l + 1) + 1.f);
    th[l] = t < 1.f ? t : 1.f;
  }
  float th9 = logf(1.5f / 9.f + 1.f);

  f32_to_bf16_vec<<<(NN * (long)NN) / (4 * 256), 256, 0, stream>>>(dist, distb);
  for (int i = 0; i < 7; ++i)
    transpose_f32_bf16<<<dim3(32, 32), 256, 0, stream>>>(
        conv_W + (size_t)i * NH * NH, convWT + (size_t)i * NH * NH, NH, NH);
  transpose_f32_bf16<<<dim3(32, 32), 256, 0, stream>>>(gat_W, gatWT, NH, NH);
  transpose_f32_bf16<<<dim3(2, 32), 256, 0, stream>>>(cls1_W, W1t, NH, 64);

  fc_kernel<<<NN, 256, 0, stream>>>(x, fc_W, fc_b, h0f, hf);
  transpose_f32_bf16<<<dim3(NH / 32, NN / 32), 256, 0, stream>>>(hf, hTb, NN, NH);

  for (int l = 0; l < 7; ++l) {
    gemm_big<<<256, 512, 0, stream>>>(distb, hTb, h0f, supf, supb);
    gemm_db<1><<<512, 256, 0, stream>>>(supb, convWT + (size_t)l * NH * NH, NH,
                                        supf, hf, nullptr, hTb, th[l]);
  }

  wv_kernel<<<NH, 256, 0, stream>>>(gat_W, gat_a, va1, va2);
  fg_kernel<<<NN, 256, 0, stream>>>(hf, va1, va2, fv, gv);
  attn_fused<<<NN, 256, 0, stream>>>(adj, fv, gv, distb);

  gemm_big<<<256, 512, 0, stream>>>(distb, hTb, h0f, supf, supb);
  gemm_db<2><<<512, 256, 0, stream>>>(supb, gatWT, NH, supf, hf, hb, nullptr, th9);

  cls_gemm<<<64, 256, 0, stream>>>(hb, W1t, cls1_b, cls3_W, cls3_b, out);
}